// Round 1
// baseline (671.893 us; speedup 1.0000x reference)
//
#include <hip/hip_runtime.h>
#include <hip/hip_bf16.h>
#include <cstdint>

#define S 2048
#define D 64
#define QT 16                 // q rows per block
#define EPAD 8                // pad shorts -> row stride 16B-aligned, 2-way banks (free)
#define ESTRIDE (S + EPAD)

typedef __attribute__((ext_vector_type(8))) short short8;
typedef __attribute__((ext_vector_type(4))) float floatx4;

static __device__ __forceinline__ short f2bf(float f) {
    union { float f; uint32_t u; } v; v.f = f;
    uint32_t r = (v.u + 0x7fffu + ((v.u >> 16) & 1u)) >> 16;   // RNE
    return (short)r;
}
static __device__ __forceinline__ float bf2f(short s) {
    union { uint32_t u; float f; } v; v.u = ((uint32_t)(uint16_t)s) << 16;
    return v.f;
}

__global__ __launch_bounds__(256, 2)
void attn_kernel(const float* __restrict__ q,
                 const float* __restrict__ k,
                 const float* __restrict__ v,
                 const float* __restrict__ bias,
                 float* __restrict__ gout,   // [BH][S][D]
                 float* __restrict__ wout)   // [BH][S][S]
{
    __shared__ __align__(16) short Elds[QT][ESTRIDE];  // unnormalized exp(logit), bf16
    __shared__ float rowsum[QT];

    const int tid  = threadIdx.x;
    const int wv   = tid >> 6;        // wave 0..3
    const int lane = tid & 63;
    const int quad = lane >> 4;
    const int l16  = lane & 15;

    const int bh = blockIdx.x >> 7;   // / (S/QT) = /128
    const int qt = blockIdx.x & 127;
    const int q0 = qt * QT;

    if (tid < QT) rowsum[tid] = 0.0f;
    __syncthreads();

    // ---- Q fragments (A-operand: A[m=l16][kk=s*32+quad*8+j]), same in all waves ----
    short8 aq[2];
    {
        const float* qrow = q + ((size_t)bh * S + q0 + l16) * D;
        #pragma unroll
        for (int s = 0; s < 2; ++s) {
            const float* p = qrow + s * 32 + quad * 8;
            #pragma unroll
            for (int j = 0; j < 8; ++j) aq[s][j] = f2bf(p[j]);
        }
    }

    // ---- QK^T + gaussian bias + exp; wave wv handles keys t*64 + wv*16 .. +15 ----
    float psum[4] = {0.f, 0.f, 0.f, 0.f};
    for (int t = 0; t < 32; ++t) {
        const int kb = t * 64 + wv * 16;
        // B-operand: B[kk][n=l16] = K[kb+l16][kk]
        short8 bk[2];
        const float* krow = k + ((size_t)bh * S + kb + l16) * D;
        #pragma unroll
        for (int s = 0; s < 2; ++s) {
            const float* p = krow + s * 32 + quad * 8;
            #pragma unroll
            for (int j = 0; j < 8; ++j) bk[s][j] = f2bf(p[j]);
        }
        floatx4 c = {0.f, 0.f, 0.f, 0.f};
        c = __builtin_amdgcn_mfma_f32_16x16x32_bf16(aq[0], bk[0], c, 0, 0, 0);
        c = __builtin_amdgcn_mfma_f32_16x16x32_bf16(aq[1], bk[1], c, 0, 0, 0);
        // C layout: row = quad*4+r (q-row), col = l16 (key kb+l16)
        #pragma unroll
        for (int r = 0; r < 4; ++r) {
            const int row = quad * 4 + r;
            const float b = bias[((size_t)bh * S + q0 + row) * S + kb + l16];
            const float logit = c[r] * 0.125f - 0.5f * b * b;   // -0.5/(0.5*2)^2 = -0.5
            const float e = __expf(logit);                       // no max-sub needed: logit <= ~6
            psum[r] += e;
            Elds[row][kb + l16] = f2bf(e);
        }
    }
    // reduce partial row sums across the 16 lanes of each quad, then across waves via LDS
    #pragma unroll
    for (int r = 0; r < 4; ++r) {
        float s0 = psum[r];
        s0 += __shfl_xor(s0, 1);
        s0 += __shfl_xor(s0, 2);
        s0 += __shfl_xor(s0, 4);
        s0 += __shfl_xor(s0, 8);
        if (l16 == 0) atomicAdd(&rowsum[quad * 4 + r], s0);
    }

    __syncthreads();   // E complete + rowsums final

    // ---- write normalized weights (coalesced 256B bursts per 16-thread row group) ----
    {
        const int r = tid >> 4;
        const int l = tid & 15;
        const float rinv = 1.0f / rowsum[r];
        float* wrow = wout + ((size_t)bh * S + q0 + r) * S;
        #pragma unroll 4
        for (int it = 0; it < 32; ++it) {
            const int col = it * 64 + l * 4;
            floatx4 o;
            #pragma unroll
            for (int j = 0; j < 4; ++j) o[j] = bf2f(Elds[r][col + j]) * rinv;
            *(floatx4*)(wrow + col) = o;
        }
    }

    // ---- PV: wave wv owns dim tile [wv*16, wv*16+16); no cross-wave reduction ----
    {
        floatx4 acc = {0.f, 0.f, 0.f, 0.f};
        const int dimc = wv * 16 + l16;
        const float* vcol = v + (size_t)bh * S * D + dimc;
        for (int sl = 0; sl < 64; ++sl) {
            const int sbase = sl * 32;
            // A-operand from LDS: A[m=l16][kk=quad*8+j] -> ds_read_b128
            short8 af = *(const short8*)&Elds[l16][sbase + quad * 8];
            // B-operand: B[kk][n=l16] = V[sbase+kk][dimc]
            short8 bf;
            #pragma unroll
            for (int j = 0; j < 8; ++j) {
                const int key = sbase + quad * 8 + j;
                bf[j] = f2bf(vcol[(size_t)key * D]);
            }
            acc = __builtin_amdgcn_mfma_f32_16x16x32_bf16(af, bf, acc, 0, 0, 0);
        }
        #pragma unroll
        for (int r = 0; r < 4; ++r) {
            const int row = quad * 4 + r;
            const float rinv = 1.0f / rowsum[row];
            gout[((size_t)bh * S + q0 + row) * D + dimc] = acc[r] * rinv;
        }
    }
}

extern "C" void kernel_launch(void* const* d_in, const int* in_sizes, int n_in,
                              void* d_out, int out_size, void* d_ws, size_t ws_size,
                              hipStream_t stream) {
    const float* q    = (const float*)d_in[0];
    const float* k    = (const float*)d_in[1];
    const float* v    = (const float*)d_in[2];
    const float* bias = (const float*)d_in[3];
    const int BH = in_sizes[0] / (S * D);          // 16
    float* gout = (float*)d_out;
    float* wout = gout + (size_t)BH * S * D;       // weights follow graph_out
    dim3 grid(BH * (S / QT));                      // 2048 blocks
    attn_kernel<<<grid, dim3(256), 0, stream>>>(q, k, v, bias, gout, wout);
}

// Round 2
// 665.083 us; speedup vs baseline: 1.0102x; 1.0102x over previous
//
#include <hip/hip_runtime.h>
#include <cstdint>

#define S 2048
#define D 64
#define QT 8                   // q rows per block (halved -> 33 KB LDS -> 4 blocks/CU)
#define EPAD 8
#define ESTRIDE (S + EPAD)     // shorts; 2056*2 = 4112 B row stride, 16B-divisible

typedef __attribute__((ext_vector_type(8))) short short8;
typedef __attribute__((ext_vector_type(4))) short short4v;
typedef __attribute__((ext_vector_type(4))) float floatx4;

static __device__ __forceinline__ unsigned short f2bf(float f) {
    union { float f; uint32_t u; } v; v.f = f;
    uint32_t r = (v.u + 0x7fffu + ((v.u >> 16) & 1u)) >> 16;   // RNE
    return (unsigned short)r;
}
static __device__ __forceinline__ float bf2f(unsigned short s) {
    union { uint32_t u; float f; } v; v.u = ((uint32_t)s) << 16;
    return v.f;
}

// ---- pre-pass 1: flat fp32 -> bf16 (for K) ----
__global__ void convert_bf16_kernel(const float* __restrict__ in,
                                    unsigned short* __restrict__ out, int n8) {
    int i = (blockIdx.x * 256 + threadIdx.x);
    if (i >= n8) return;
    const float* p = in + (size_t)i * 8;
    short8 o;
    #pragma unroll
    for (int j = 0; j < 8; ++j) o[j] = (short)f2bf(p[j]);
    *(short8*)(out + (size_t)i * 8) = o;
}

// ---- pre-pass 2: V [BH][S][D] fp32 -> Vt [BH][D][S] bf16 ----
__global__ void transpose_v_kernel(const float* __restrict__ v,
                                   unsigned short* __restrict__ vt) {
    __shared__ unsigned short tile[64][72];
    const int tid = threadIdx.x;
    const int bh = blockIdx.x >> 5;        // S/64 = 32 tiles per bh
    const int s0 = (blockIdx.x & 31) * 64;
    #pragma unroll
    for (int rep = 0; rep < 16; ++rep) {
        int idx = rep * 256 + tid;
        int sl = idx >> 6, d = idx & 63;
        tile[sl][d] = f2bf(v[((size_t)bh * S + s0 + sl) * D + d]);
    }
    __syncthreads();
    #pragma unroll
    for (int rep = 0; rep < 16; ++rep) {
        int idx = rep * 256 + tid;
        int d = idx >> 6, sl = idx & 63;
        vt[((size_t)bh * D + d) * S + s0 + sl] = tile[sl][d];
    }
}

template <bool PRE>
__global__ __launch_bounds__(256, 4)
void attn_kernel(const float* __restrict__ q,
                 const float* __restrict__ k,
                 const float* __restrict__ v,
                 const float* __restrict__ bias,
                 const unsigned short* __restrict__ kb16,  // [BH][S][D] bf16
                 const unsigned short* __restrict__ vt16,  // [BH][D][S] bf16
                 float* __restrict__ gout,   // [BH][S][D]
                 float* __restrict__ wout)   // [BH][S][S]
{
    __shared__ __align__(16) unsigned short Elds[QT][ESTRIDE];
    __shared__ float rowsum[QT];

    const int tid  = threadIdx.x;
    const int wv   = tid >> 6;
    const int lane = tid & 63;
    const int quad = lane >> 4;
    const int l16  = lane & 15;

    const int bh = blockIdx.x >> 8;        // / (S/QT) = /256
    const int qt = blockIdx.x & 255;
    const int q0 = qt * QT;

    if (tid < QT) rowsum[tid] = 0.0f;
    __syncthreads();

    // ---- Q fragment: A[m=l16][kk=s*32+quad*8+j]; rows 8..15 duplicate 0..7 ----
    short8 aq[2];
    {
        const float* qrow = q + ((size_t)bh * S + q0 + (l16 & 7)) * D;
        #pragma unroll
        for (int s = 0; s < 2; ++s) {
            const float* p = qrow + s * 32 + quad * 8;
            #pragma unroll
            for (int j = 0; j < 8; ++j) aq[s][j] = (short)f2bf(p[j]);
        }
    }

    // ---- QK^T + gaussian bias + exp; wave wv handles keys t*64 + wv*16 ----
    float psum[4] = {0.f, 0.f, 0.f, 0.f};
    for (int t = 0; t < 32; ++t) {
        const int kb = t * 64 + wv * 16;
        short8 bk[2];
        if (PRE) {
            const unsigned short* kr = kb16 + ((size_t)bh * S + kb + l16) * D;
            bk[0] = *(const short8*)(kr + quad * 8);
            bk[1] = *(const short8*)(kr + 32 + quad * 8);
        } else {
            const float* krow = k + ((size_t)bh * S + kb + l16) * D;
            #pragma unroll
            for (int s = 0; s < 2; ++s) {
                const float* p = krow + s * 32 + quad * 8;
                #pragma unroll
                for (int j = 0; j < 8; ++j) bk[s][j] = (short)f2bf(p[j]);
            }
        }
        floatx4 c = {0.f, 0.f, 0.f, 0.f};
        c = __builtin_amdgcn_mfma_f32_16x16x32_bf16(aq[0], bk[0], c, 0, 0, 0);
        c = __builtin_amdgcn_mfma_f32_16x16x32_bf16(aq[1], bk[1], c, 0, 0, 0);
        // C layout: row = quad*4+r (q-row, valid < 8 -> quad<2), col = l16
        if (quad < 2) {
            #pragma unroll
            for (int r = 0; r < 4; ++r) {
                const int row = quad * 4 + r;
                const float b = bias[((size_t)bh * S + q0 + row) * S + kb + l16];
                const float logit = c[r] * 0.125f - 0.5f * b * b;
                const float e = __expf(logit);
                psum[r] += e;
                Elds[row][kb + l16] = f2bf(e);
            }
        }
    }
    if (quad < 2) {
        #pragma unroll
        for (int r = 0; r < 4; ++r) {
            float s0 = psum[r];
            s0 += __shfl_xor(s0, 1);
            s0 += __shfl_xor(s0, 2);
            s0 += __shfl_xor(s0, 4);
            s0 += __shfl_xor(s0, 8);
            if (l16 == 0) atomicAdd(&rowsum[quad * 4 + r], s0);
        }
    }

    __syncthreads();

    // ---- write normalized weights: 32 threads per row, dwordx4 stores ----
    {
        const int r = tid >> 5;          // 0..7
        const int l = tid & 31;
        const float rinv = 1.0f / rowsum[r];
        float* wrow = wout + ((size_t)bh * S + q0 + r) * S;
        #pragma unroll 4
        for (int it = 0; it < 16; ++it) {
            const int col = it * 128 + l * 4;
            short4v ev = *(const short4v*)&Elds[r][col];
            floatx4 o;
            #pragma unroll
            for (int j = 0; j < 4; ++j) o[j] = bf2f((unsigned short)ev[j]) * rinv;
            *(floatx4*)(wrow + col) = o;
        }
    }

    // ---- PV: wave wv owns dim tile [wv*16, wv*16+16) ----
    {
        floatx4 acc = {0.f, 0.f, 0.f, 0.f};
        const int dimc = wv * 16 + l16;
        if (PRE) {
            const unsigned short* vrow = vt16 + ((size_t)bh * D + dimc) * S;
            for (int sl = 0; sl < 64; ++sl) {
                const int sbase = sl * 32;
                short8 af = *(const short8*)&Elds[l16 & 7][sbase + quad * 8];
                short8 bfv = *(const short8*)(vrow + sbase + quad * 8);
                acc = __builtin_amdgcn_mfma_f32_16x16x32_bf16(af, bfv, acc, 0, 0, 0);
            }
        } else {
            const float* vcol = v + (size_t)bh * S * D + dimc;
            for (int sl = 0; sl < 64; ++sl) {
                const int sbase = sl * 32;
                short8 af = *(const short8*)&Elds[l16 & 7][sbase + quad * 8];
                short8 bfv;
                #pragma unroll
                for (int j = 0; j < 8; ++j)
                    bfv[j] = (short)f2bf(vcol[(size_t)(sbase + quad * 8 + j) * D]);
                acc = __builtin_amdgcn_mfma_f32_16x16x32_bf16(af, bfv, acc, 0, 0, 0);
            }
        }
        if (quad < 2) {
            #pragma unroll
            for (int r = 0; r < 4; ++r) {
                const int row = quad * 4 + r;
                const float rinv = 1.0f / rowsum[row];
                gout[((size_t)bh * S + q0 + row) * D + dimc] = acc[r] * rinv;
            }
        }
    }
}

extern "C" void kernel_launch(void* const* d_in, const int* in_sizes, int n_in,
                              void* d_out, int out_size, void* d_ws, size_t ws_size,
                              hipStream_t stream) {
    const float* q    = (const float*)d_in[0];
    const float* k    = (const float*)d_in[1];
    const float* v    = (const float*)d_in[2];
    const float* bias = (const float*)d_in[3];
    const int BH = in_sizes[0] / (S * D);          // 16
    float* gout = (float*)d_out;
    float* wout = gout + (size_t)BH * S * D;

    const size_t nkv = (size_t)BH * S * D;         // 2,097,152 elements
    const bool pre = ws_size >= nkv * 2 * sizeof(unsigned short);

    dim3 grid(BH * (S / QT));                      // 4096 blocks

    if (pre) {
        unsigned short* kb16 = (unsigned short*)d_ws;
        unsigned short* vt16 = kb16 + nkv;
        int n8 = (int)(nkv / 8);
        convert_bf16_kernel<<<(n8 + 255) / 256, 256, 0, stream>>>(k, kb16, n8);
        transpose_v_kernel<<<BH * (S / 64), 256, 0, stream>>>(v, vt16);
        attn_kernel<true><<<grid, dim3(256), 0, stream>>>(q, k, v, bias, kb16, vt16, gout, wout);
    } else {
        attn_kernel<false><<<grid, dim3(256), 0, stream>>>(q, k, v, bias, nullptr, nullptr, gout, wout);
    }
}